// Round 3
// baseline (348.907 us; speedup 1.0000x reference)
//
#include <hip/hip_runtime.h>

// ClusteringLayer v3 on gfx950 — v2 + contiguous store epilogue.
// q = normalize(1/(1+dist2)), dist2 = xsq + csq - 2 x.c (exact fp32 xsq/csq;
// cross via bf16 MFMA, one-sided split x = x_hi + x_lo => 2 MFMA passes).
//
// v2 finding: VALU 35->14%, LDS conflicts ->0, time unchanged => neither was
// the bottleneck. v3 changes ONLY the store path: each wave transposes its
// 16x256 result through wave-private LDS (no barriers; in-order per-wave DS
// ops + lgkmcnt drain, double-buffered) and stores full 1 KB output rows with
// single global_store_dwordx4 instructions (16 contiguous stores per wave vs
// 64 scattered dword stores with 64 B segments).
//
// Round-2 bench was an infra failure (container acquire), not a kernel
// verdict — resubmitting unchanged.

#define DIM 128
#define NK  256

typedef __attribute__((ext_vector_type(8))) short short8;
typedef __attribute__((ext_vector_type(4))) float floatx4;

__device__ __forceinline__ unsigned short bf16_rne(float f) {
    unsigned int u = __float_as_uint(f);
    return (unsigned short)((u + 0x7fffu + ((u >> 16) & 1u)) >> 16);
}
__device__ __forceinline__ float bf16_f(unsigned short h) {
    return __uint_as_float(((unsigned int)h) << 16);
}

// ---------------------------------------------------------------------------
// prep: blocks 0-7 pack C into B-fragment order: ushort16B frag index
//   gid = ct*256 + ks*64 + lane  holds  c_bf16[col = ct*16 + (lane&15)]
//                                        [k = ks*32 + (lane>>4)*8 + j], j=0..7
// block 8: exact fp32 csq[col] = sum_k c[col][k]^2.
// ---------------------------------------------------------------------------
__global__ void prep_clusters(const float* __restrict__ c,
                              unsigned short* __restrict__ wb,
                              float* __restrict__ wcsq)
{
    if (blockIdx.x < 8) {
        const int gid  = blockIdx.x * 512 + threadIdx.x;  // 0..4095
        const int lane = gid & 63;
        const int ks   = (gid >> 6) & 3;
        const int ct   = gid >> 8;
        const int lm   = lane & 15;
        const int q4   = lane >> 4;
        const int col  = ct * 16 + lm;
        const float4* cg = (const float4*)(c + col * DIM + ks * 32 + q4 * 8);
        float4 v0 = cg[0], v1 = cg[1];
        const float* f0 = (const float*)&v0;
        const float* f1 = (const float*)&v1;
        union { unsigned short u[8]; short8 v; } B;
        #pragma unroll
        for (int i = 0; i < 4; ++i) B.u[i] = bf16_rne(f0[i]);
        #pragma unroll
        for (int i = 0; i < 4; ++i) B.u[4 + i] = bf16_rne(f1[i]);
        ((short8*)wb)[gid] = B.v;
    } else {
        const int t = threadIdx.x;
        const int col = t >> 1, half = t & 1;
        const float4* cg = (const float4*)(c + col * DIM + half * 64);
        float s = 0.f;
        #pragma unroll
        for (int i = 0; i < 16; ++i) {
            float4 v = cg[i];
            s = fmaf(v.x, v.x, s); s = fmaf(v.y, v.y, s);
            s = fmaf(v.z, v.z, s); s = fmaf(v.w, v.w, s);
        }
        s += __shfl_xor(s, 1);   // partner thread, same col
        if (!half) wcsq[col] = s;
    }
}

// ---------------------------------------------------------------------------
// main: 256 threads = 4 independent waves; wave w -> rows [bid*64+16w, +16).
// ---------------------------------------------------------------------------
__global__ __launch_bounds__(256, 3) void cluster_q_v3(
    const float* __restrict__ x,
    const unsigned short* __restrict__ wb,
    const float* __restrict__ wcsq,
    float* __restrict__ out)
{
    __shared__ float csq_s[NK];
    // wave-private transpose buffers: [wave][dbuf][q4-row][256+8 pad floats]
    __shared__ __align__(16) float lt[4][2][4][264];

    const int tid  = threadIdx.x;
    csq_s[tid] = wcsq[tid];          // 256 threads load 256-entry table

    const int wave = tid >> 6;
    const int lane = tid & 63;
    const int lm   = lane & 15;      // A row / C col within tile
    const int q4   = lane >> 4;
    const size_t row0 = (size_t)blockIdx.x * 64 + wave * 16;

    // ---- A fragments (hi/lo) in registers + exact fp32 row norm ----
    // lane covers row lm, k = ks*32 + q4*8 + j
    short8 ah[4], al[4];
    float xq = 0.f;
    const float* xrow = x + (row0 + lm) * DIM;
    #pragma unroll
    for (int ks = 0; ks < 4; ++ks) {
        const float4* xg = (const float4*)(xrow + ks * 32 + q4 * 8);
        float4 v0 = xg[0], v1 = xg[1];
        const float* f0 = (const float*)&v0;
        const float* f1 = (const float*)&v1;
        union { unsigned short u[8]; short8 v; } H, L;
        #pragma unroll
        for (int i = 0; i < 4; ++i) {
            float f = f0[i];
            xq = fmaf(f, f, xq);
            unsigned short h = bf16_rne(f);
            H.u[i] = h;
            L.u[i] = bf16_rne(f - bf16_f(h));
        }
        #pragma unroll
        for (int i = 0; i < 4; ++i) {
            float f = f1[i];
            xq = fmaf(f, f, xq);
            unsigned short h = bf16_rne(f);
            H.u[4 + i] = h;
            L.u[4 + i] = bf16_rne(f - bf16_f(h));
        }
        ah[ks] = H.v;
        al[ks] = L.v;
    }
    // lane holds k-subset for fixed q4; sum over the 4 q4 groups -> full ||x_row||^2
    xq += __shfl_xor(xq, 16);
    xq += __shfl_xor(xq, 32);

    // ---- K loop: 16 col-tiles, B-frags streamed from L2-resident workspace ----
    floatx4 acc[16];
    #pragma unroll
    for (int ct = 0; ct < 16; ++ct) {
        const short8* bp = (const short8*)wb + (ct * 256 + lane);
        floatx4 a = (floatx4){0.f, 0.f, 0.f, 0.f};
        #pragma unroll
        for (int ks = 0; ks < 4; ++ks) {
            short8 b = bp[ks * 64];   // fully coalesced: 64 lanes x 16B contiguous
            a = __builtin_amdgcn_mfma_f32_16x16x32_bf16(ah[ks], b, a, 0, 0, 0);
            a = __builtin_amdgcn_mfma_f32_16x16x32_bf16(al[ks], b, a, 0, 0, 0);
        }
        acc[ct] = a;
    }

    __syncthreads();   // csq_s ready (placed late: zero wait in practice)

    // xsq for this lane's C rows (row = q4*4 + r lives in lanes with lm == that)
    float xs4[4];
    #pragma unroll
    for (int r = 0; r < 4; ++r) xs4[r] = __shfl(xq, q4 * 4 + r);

    // ---- epilogue pass 1: q = 1/(1+dist2), in-wave row sums ----
    float rsum[4] = {0.f, 0.f, 0.f, 0.f};
    #pragma unroll
    for (int ct = 0; ct < 16; ++ct) {
        const float cq = csq_s[ct * 16 + lm];
        #pragma unroll
        for (int r = 0; r < 4; ++r) {
            float d2 = fmaf(-2.f, acc[ct][r], xs4[r] + cq);
            d2 = fmaxf(d2, 0.f);
            float q = __builtin_amdgcn_rcpf(1.f + d2);
            acc[ct][r] = q;
            rsum[r] += q;
        }
    }
    #pragma unroll
    for (int r = 0; r < 4; ++r) {
        rsum[r] += __shfl_xor(rsum[r], 1);
        rsum[r] += __shfl_xor(rsum[r], 2);
        rsum[r] += __shfl_xor(rsum[r], 4);
        rsum[r] += __shfl_xor(rsum[r], 8);
        rsum[r] = __builtin_amdgcn_rcpf(rsum[r]);
    }

    // ---- epilogue pass 2: wave-private LDS transpose -> contiguous stores ----
    // Per r-phase: lane (q4,lm) scatters acc[ct][r]*inv into LDS row q4
    // (2-way bank pattern = free), lgkmcnt(0) drain, then 4 full-BW
    // ds_read_b128 + 4 global_store_dwordx4: each store = one full 1 KB
    // output row, 64 lanes contiguous. No barriers: wave-private buffer,
    // per-wave DS ops are in-order; each phase's drain also covers the
    // previous phase's reads (double-buffered on r&1).
    #pragma unroll
    for (int r = 0; r < 4; ++r) {
        float* lw = &lt[wave][r & 1][q4][0];
        const float inv = rsum[r];
        #pragma unroll
        for (int ct = 0; ct < 16; ++ct)
            lw[ct * 16 + lm] = acc[ct][r] * inv;
        asm volatile("s_waitcnt lgkmcnt(0)" ::: "memory");
        #pragma unroll
        for (int j = 0; j < 4; ++j) {
            const float4 v = *(const float4*)&lt[wave][r & 1][j][lane * 4];
            *(float4*)(out + (row0 + j * 4 + r) * NK + lane * 4) = v;
        }
    }
}

extern "C" void kernel_launch(void* const* d_in, const int* in_sizes, int n_in,
                              void* d_out, int out_size, void* d_ws, size_t ws_size,
                              hipStream_t stream) {
    const float* x = (const float*)d_in[0];   // [200000, 128] fp32
    const float* c = (const float*)d_in[1];   // [256, 128] fp32
    float* out = (float*)d_out;               // [200000, 256] fp32
    unsigned short* wb = (unsigned short*)d_ws;            // 64 KiB packed B
    float* wcsq = (float*)((char*)d_ws + 65536);           // 1 KiB csq
    const int N = in_sizes[0] / DIM;          // 200000 = 3125 * 64

    prep_clusters<<<dim3(9), dim3(512), 0, stream>>>(c, wb, wcsq);
    cluster_q_v3<<<dim3(N / 64), dim3(256), 0, stream>>>(x, wb, wcsq, out);
}

// Round 5
// 333.881 us; speedup vs baseline: 1.0450x; 1.0450x over previous
//
#include <hip/hip_runtime.h>

// ClusteringLayer v4b on gfx950 — v3 + NONTEMPORAL output stores (fixed:
// __builtin_nontemporal_store requires a clang ext_vector type, not HIP's
// float4 class — use floatx4).
// q = normalize(1/(1+dist2)), dist2 = xsq + csq - 2 x.c (exact fp32 xsq/csq;
// cross via bf16 MFMA, one-sided split x = x_hi + x_lo => 2 MFMA passes).
//
// Findings so far: VALU 14%, MFMA 7%, LDS conflicts ~0, stores contiguous —
// time pinned at ~140 µs across three structurally different kernels.
// Sustained write rate stuck at 1.43 TB/s (even the harness memset runs at
// ~1.4 TB/s). Theory: write-back/write-allocate L2->L3 dirty-evict chain
// caps the stream. v4 changes ONE thing: output stores are nontemporal
// (global_store_dwordx4 nt — no-allocate, stream to HBM).

#define DIM 128
#define NK  256

typedef __attribute__((ext_vector_type(8))) short short8;
typedef __attribute__((ext_vector_type(4))) float floatx4;

__device__ __forceinline__ unsigned short bf16_rne(float f) {
    unsigned int u = __float_as_uint(f);
    return (unsigned short)((u + 0x7fffu + ((u >> 16) & 1u)) >> 16);
}
__device__ __forceinline__ float bf16_f(unsigned short h) {
    return __uint_as_float(((unsigned int)h) << 16);
}

// ---------------------------------------------------------------------------
// prep: blocks 0-7 pack C into B-fragment order: ushort16B frag index
//   gid = ct*256 + ks*64 + lane  holds  c_bf16[col = ct*16 + (lane&15)]
//                                        [k = ks*32 + (lane>>4)*8 + j], j=0..7
// block 8: exact fp32 csq[col] = sum_k c[col][k]^2.
// ---------------------------------------------------------------------------
__global__ void prep_clusters(const float* __restrict__ c,
                              unsigned short* __restrict__ wb,
                              float* __restrict__ wcsq)
{
    if (blockIdx.x < 8) {
        const int gid  = blockIdx.x * 512 + threadIdx.x;  // 0..4095
        const int lane = gid & 63;
        const int ks   = (gid >> 6) & 3;
        const int ct   = gid >> 8;
        const int lm   = lane & 15;
        const int q4   = lane >> 4;
        const int col  = ct * 16 + lm;
        const float4* cg = (const float4*)(c + col * DIM + ks * 32 + q4 * 8);
        float4 v0 = cg[0], v1 = cg[1];
        const float* f0 = (const float*)&v0;
        const float* f1 = (const float*)&v1;
        union { unsigned short u[8]; short8 v; } B;
        #pragma unroll
        for (int i = 0; i < 4; ++i) B.u[i] = bf16_rne(f0[i]);
        #pragma unroll
        for (int i = 0; i < 4; ++i) B.u[4 + i] = bf16_rne(f1[i]);
        ((short8*)wb)[gid] = B.v;
    } else {
        const int t = threadIdx.x;
        const int col = t >> 1, half = t & 1;
        const float4* cg = (const float4*)(c + col * DIM + half * 64);
        float s = 0.f;
        #pragma unroll
        for (int i = 0; i < 16; ++i) {
            float4 v = cg[i];
            s = fmaf(v.x, v.x, s); s = fmaf(v.y, v.y, s);
            s = fmaf(v.z, v.z, s); s = fmaf(v.w, v.w, s);
        }
        s += __shfl_xor(s, 1);   // partner thread, same col
        if (!half) wcsq[col] = s;
    }
}

// ---------------------------------------------------------------------------
// main: 256 threads = 4 independent waves; wave w -> rows [bid*64+16w, +16).
// ---------------------------------------------------------------------------
__global__ __launch_bounds__(256, 3) void cluster_q_v4(
    const float* __restrict__ x,
    const unsigned short* __restrict__ wb,
    const float* __restrict__ wcsq,
    float* __restrict__ out)
{
    __shared__ float csq_s[NK];
    // wave-private transpose buffers: [wave][dbuf][q4-row][256+8 pad floats]
    __shared__ __align__(16) float lt[4][2][4][264];

    const int tid  = threadIdx.x;
    csq_s[tid] = wcsq[tid];          // 256 threads load 256-entry table

    const int wave = tid >> 6;
    const int lane = tid & 63;
    const int lm   = lane & 15;      // A row / C col within tile
    const int q4   = lane >> 4;
    const size_t row0 = (size_t)blockIdx.x * 64 + wave * 16;

    // ---- A fragments (hi/lo) in registers + exact fp32 row norm ----
    // lane covers row lm, k = ks*32 + q4*8 + j
    short8 ah[4], al[4];
    float xq = 0.f;
    const float* xrow = x + (row0 + lm) * DIM;
    #pragma unroll
    for (int ks = 0; ks < 4; ++ks) {
        const float4* xg = (const float4*)(xrow + ks * 32 + q4 * 8);
        float4 v0 = xg[0], v1 = xg[1];
        const float* f0 = (const float*)&v0;
        const float* f1 = (const float*)&v1;
        union { unsigned short u[8]; short8 v; } H, L;
        #pragma unroll
        for (int i = 0; i < 4; ++i) {
            float f = f0[i];
            xq = fmaf(f, f, xq);
            unsigned short h = bf16_rne(f);
            H.u[i] = h;
            L.u[i] = bf16_rne(f - bf16_f(h));
        }
        #pragma unroll
        for (int i = 0; i < 4; ++i) {
            float f = f1[i];
            xq = fmaf(f, f, xq);
            unsigned short h = bf16_rne(f);
            H.u[4 + i] = h;
            L.u[4 + i] = bf16_rne(f - bf16_f(h));
        }
        ah[ks] = H.v;
        al[ks] = L.v;
    }
    // lane holds k-subset for fixed q4; sum over the 4 q4 groups -> full ||x_row||^2
    xq += __shfl_xor(xq, 16);
    xq += __shfl_xor(xq, 32);

    // ---- K loop: 16 col-tiles, B-frags streamed from L2-resident workspace ----
    floatx4 acc[16];
    #pragma unroll
    for (int ct = 0; ct < 16; ++ct) {
        const short8* bp = (const short8*)wb + (ct * 256 + lane);
        floatx4 a = (floatx4){0.f, 0.f, 0.f, 0.f};
        #pragma unroll
        for (int ks = 0; ks < 4; ++ks) {
            short8 b = bp[ks * 64];   // fully coalesced: 64 lanes x 16B contiguous
            a = __builtin_amdgcn_mfma_f32_16x16x32_bf16(ah[ks], b, a, 0, 0, 0);
            a = __builtin_amdgcn_mfma_f32_16x16x32_bf16(al[ks], b, a, 0, 0, 0);
        }
        acc[ct] = a;
    }

    __syncthreads();   // csq_s ready (placed late: zero wait in practice)

    // xsq for this lane's C rows (row = q4*4 + r lives in lanes with lm == that)
    float xs4[4];
    #pragma unroll
    for (int r = 0; r < 4; ++r) xs4[r] = __shfl(xq, q4 * 4 + r);

    // ---- epilogue pass 1: q = 1/(1+dist2), in-wave row sums ----
    float rsum[4] = {0.f, 0.f, 0.f, 0.f};
    #pragma unroll
    for (int ct = 0; ct < 16; ++ct) {
        const float cq = csq_s[ct * 16 + lm];
        #pragma unroll
        for (int r = 0; r < 4; ++r) {
            float d2 = fmaf(-2.f, acc[ct][r], xs4[r] + cq);
            d2 = fmaxf(d2, 0.f);
            float q = __builtin_amdgcn_rcpf(1.f + d2);
            acc[ct][r] = q;
            rsum[r] += q;
        }
    }
    #pragma unroll
    for (int r = 0; r < 4; ++r) {
        rsum[r] += __shfl_xor(rsum[r], 1);
        rsum[r] += __shfl_xor(rsum[r], 2);
        rsum[r] += __shfl_xor(rsum[r], 4);
        rsum[r] += __shfl_xor(rsum[r], 8);
        rsum[r] = __builtin_amdgcn_rcpf(rsum[r]);
    }

    // ---- epilogue pass 2: wave-private LDS transpose -> NT contiguous stores --
    // Per r-phase: lane (q4,lm) scatters acc[ct][r]*inv into LDS row q4
    // (2-way bank pattern = free), lgkmcnt(0) drain, then 4 full-BW
    // ds_read_b128 + 4 nontemporal global_store_dwordx4: each store = one
    // full 1 KB output row, 64 lanes contiguous, no-allocate (nt) so the
    // write stream bypasses the L2/L3 write-allocate/evict chain.
    #pragma unroll
    for (int r = 0; r < 4; ++r) {
        float* lw = &lt[wave][r & 1][q4][0];
        const float inv = rsum[r];
        #pragma unroll
        for (int ct = 0; ct < 16; ++ct)
            lw[ct * 16 + lm] = acc[ct][r] * inv;
        asm volatile("s_waitcnt lgkmcnt(0)" ::: "memory");
        #pragma unroll
        for (int j = 0; j < 4; ++j) {
            const floatx4 v = *(const floatx4*)&lt[wave][r & 1][j][lane * 4];
            __builtin_nontemporal_store(v, (floatx4*)(out + (row0 + j * 4 + r) * NK + lane * 4));
        }
    }
}

extern "C" void kernel_launch(void* const* d_in, const int* in_sizes, int n_in,
                              void* d_out, int out_size, void* d_ws, size_t ws_size,
                              hipStream_t stream) {
    const float* x = (const float*)d_in[0];   // [200000, 128] fp32
    const float* c = (const float*)d_in[1];   // [256, 128] fp32
    float* out = (float*)d_out;               // [200000, 256] fp32
    unsigned short* wb = (unsigned short*)d_ws;            // 64 KiB packed B
    float* wcsq = (float*)((char*)d_ws + 65536);           // 1 KiB csq
    const int N = in_sizes[0] / DIM;          // 200000 = 3125 * 64

    prep_clusters<<<dim3(9), dim3(512), 0, stream>>>(c, wb, wcsq);
    cluster_q_v4<<<dim3(N / 64), dim3(256), 0, stream>>>(x, wb, wcsq, out);
}

// Round 6
// 289.907 us; speedup vs baseline: 1.2035x; 1.1517x over previous
//
#include <hip/hip_runtime.h>

// ClusteringLayer v5 on gfx950 — persistent blocks + continuous write stream.
// q = normalize(1/(1+dist2)), dist2 = xsq + csq - 2 x.c (exact fp32 xsq/csq;
// cross via bf16 MFMA, one-sided split x = x_hi + x_lo => 2 MFMA passes).
//
// Findings: 4 structurally different kernels all pinned at ~1.5 TB/s write
// rate (copy ubench writes 3.15). Theory: terminal store-burst + vmcnt(0)
// end-drain serializes blocks (vmcnt is FIFO: any load-consume drains older
// stores). v5: persistent blocks (grid 512, ~6 tiles each); B staged into
// LDS once per block so the K-loop has ZERO vmem loads (lgkmcnt only); next
// tile's x prefetched BEFORE current tile's stores (sched_barrier-pinned) so
// outstanding NT stores (16/strip) ride across strips — the write queue
// never drains until block end.

#define DIM 128
#define NK  256

typedef __attribute__((ext_vector_type(8))) short short8;
typedef __attribute__((ext_vector_type(4))) float floatx4;

__device__ __forceinline__ unsigned short bf16_rne(float f) {
    unsigned int u = __float_as_uint(f);
    return (unsigned short)((u + 0x7fffu + ((u >> 16) & 1u)) >> 16);
}
__device__ __forceinline__ float bf16_f(unsigned short h) {
    return __uint_as_float(((unsigned int)h) << 16);
}

// ---------------------------------------------------------------------------
// prep: blocks 0-7 pack C into B-fragment order: 16B frag index
//   gid = ct*256 + ks*64 + lane  holds  c_bf16[col = ct*16 + (lane&15)]
//                                        [k = ks*32 + (lane>>4)*8 + j], j=0..7
// block 8: exact fp32 csq[col] = sum_k c[col][k]^2.
// ---------------------------------------------------------------------------
__global__ void prep_clusters(const float* __restrict__ c,
                              unsigned short* __restrict__ wb,
                              float* __restrict__ wcsq)
{
    if (blockIdx.x < 8) {
        const int gid  = blockIdx.x * 512 + threadIdx.x;  // 0..4095
        const int lane = gid & 63;
        const int ks   = (gid >> 6) & 3;
        const int ct   = gid >> 8;
        const int lm   = lane & 15;
        const int q4   = lane >> 4;
        const int col  = ct * 16 + lm;
        const float4* cg = (const float4*)(c + col * DIM + ks * 32 + q4 * 8);
        float4 v0 = cg[0], v1 = cg[1];
        const float* f0 = (const float*)&v0;
        const float* f1 = (const float*)&v1;
        union { unsigned short u[8]; short8 v; } B;
        #pragma unroll
        for (int i = 0; i < 4; ++i) B.u[i] = bf16_rne(f0[i]);
        #pragma unroll
        for (int i = 0; i < 4; ++i) B.u[4 + i] = bf16_rne(f1[i]);
        ((short8*)wb)[gid] = B.v;
    } else {
        const int t = threadIdx.x;
        const int col = t >> 1, half = t & 1;
        const float4* cg = (const float4*)(c + col * DIM + half * 64);
        float s = 0.f;
        #pragma unroll
        for (int i = 0; i < 16; ++i) {
            float4 v = cg[i];
            s = fmaf(v.x, v.x, s); s = fmaf(v.y, v.y, s);
            s = fmaf(v.z, v.z, s); s = fmaf(v.w, v.w, s);
        }
        s += __shfl_xor(s, 1);   // partner thread, same col
        if (!half) wcsq[col] = s;
    }
}

__device__ __forceinline__ void prefetch_x(const float* __restrict__ x,
                                           int t, int wave, int lm, int q4,
                                           float4 pf[8]) {
    const float* xr = x + ((size_t)t * 64 + wave * 16 + lm) * DIM;
    #pragma unroll
    for (int ks = 0; ks < 4; ++ks) {
        const float4* xg = (const float4*)(xr + ks * 32 + q4 * 8);
        pf[2 * ks]     = xg[0];
        pf[2 * ks + 1] = xg[1];
    }
}

// ---------------------------------------------------------------------------
// main: 256 threads = 4 independent waves; persistent over row-tiles.
// wave w of tile t -> rows [t*64 + 16w, +16).
// ---------------------------------------------------------------------------
__global__ __launch_bounds__(256, 1) void cluster_q_v5(
    const float* __restrict__ x,
    const unsigned short* __restrict__ wb,
    const float* __restrict__ wcsq,
    float* __restrict__ out,
    const int NT)
{
    __shared__ __align__(16) unsigned short bs[32768];   // 64 KiB: B fragments
    __shared__ float csq_s[NK];
    __shared__ __align__(16) float lt[4][2][4][264];     // transpose buffers

    const int tid  = threadIdx.x;
    const int wave = tid >> 6;
    const int lane = tid & 63;
    const int lm   = lane & 15;
    const int q4   = lane >> 4;

    // ---- stage full B (64 KiB) + csq into LDS, once per block ----
    csq_s[tid] = wcsq[tid];
    for (int i = tid; i < 4096; i += 256) {
        float4 v = ((const float4*)wb)[i];
        *(float4*)&bs[i * 8] = v;
    }
    __syncthreads();   // the only barrier

    float4 pf[8];
    int t = blockIdx.x;
    if (t < NT) prefetch_x(x, t, wave, lm, q4, pf);

    while (t < NT) {
        // ---- convert prefetched x -> A fragments (hi/lo) + exact row norm --
        short8 ah[4], al[4];
        float xq = 0.f;
        #pragma unroll
        for (int ks = 0; ks < 4; ++ks) {
            const float* f0 = (const float*)&pf[2 * ks];
            const float* f1 = (const float*)&pf[2 * ks + 1];
            union { unsigned short u[8]; short8 v; } H, L;
            #pragma unroll
            for (int i = 0; i < 4; ++i) {
                float f = f0[i];
                xq = fmaf(f, f, xq);
                unsigned short h = bf16_rne(f);
                H.u[i] = h;
                L.u[i] = bf16_rne(f - bf16_f(h));
            }
            #pragma unroll
            for (int i = 0; i < 4; ++i) {
                float f = f1[i];
                xq = fmaf(f, f, xq);
                unsigned short h = bf16_rne(f);
                H.u[4 + i] = h;
                L.u[4 + i] = bf16_rne(f - bf16_f(h));
            }
            ah[ks] = H.v;
            al[ks] = L.v;
        }
        xq += __shfl_xor(xq, 16);
        xq += __shfl_xor(xq, 32);

        // ---- K loop: B from LDS (zero vmem ops) ----
        floatx4 acc[16];
        #pragma unroll
        for (int ct = 0; ct < 16; ++ct) {
            floatx4 a = (floatx4){0.f, 0.f, 0.f, 0.f};
            #pragma unroll
            for (int ks = 0; ks < 4; ++ks) {
                short8 b = *(const short8*)&bs[(ct * 256 + ks * 64 + lane) * 8];
                a = __builtin_amdgcn_mfma_f32_16x16x32_bf16(ah[ks], b, a, 0, 0, 0);
                a = __builtin_amdgcn_mfma_f32_16x16x32_bf16(al[ks], b, a, 0, 0, 0);
            }
            acc[ct] = a;
        }

        const int tn = t + (int)gridDim.x;
        // prefetch next tile BEFORE this tile's stores (vmcnt FIFO: loads
        // older than stores => consuming them tolerates outstanding stores)
        if (tn < NT) prefetch_x(x, tn, wave, lm, q4, pf);

        // ---- epilogue: q = 1/(1+dist2), in-wave row sums ----
        float xs4[4];
        #pragma unroll
        for (int r = 0; r < 4; ++r) xs4[r] = __shfl(xq, q4 * 4 + r);

        float rsum[4] = {0.f, 0.f, 0.f, 0.f};
        #pragma unroll
        for (int ct = 0; ct < 16; ++ct) {
            const float cq = csq_s[ct * 16 + lm];
            #pragma unroll
            for (int r = 0; r < 4; ++r) {
                float d2 = fmaf(-2.f, acc[ct][r], xs4[r] + cq);
                d2 = fmaxf(d2, 0.f);
                float q = __builtin_amdgcn_rcpf(1.f + d2);
                acc[ct][r] = q;
                rsum[r] += q;
            }
        }
        #pragma unroll
        for (int r = 0; r < 4; ++r) {
            rsum[r] += __shfl_xor(rsum[r], 1);
            rsum[r] += __shfl_xor(rsum[r], 2);
            rsum[r] += __shfl_xor(rsum[r], 4);
            rsum[r] += __shfl_xor(rsum[r], 8);
            rsum[r] = __builtin_amdgcn_rcpf(rsum[r]);
        }

        // pin: prefetch issue stays above the store burst
        __builtin_amdgcn_sched_barrier(0);

        // ---- wave-private LDS transpose -> 16 contiguous NT dwordx4 stores --
        #pragma unroll
        for (int r = 0; r < 4; ++r) {
            float* lw = &lt[wave][r & 1][q4][0];
            const float inv = rsum[r];
            #pragma unroll
            for (int ct = 0; ct < 16; ++ct)
                lw[ct * 16 + lm] = acc[ct][r] * inv;
            asm volatile("s_waitcnt lgkmcnt(0)" ::: "memory");
            #pragma unroll
            for (int j = 0; j < 4; ++j) {
                const floatx4 v = *(const floatx4*)&lt[wave][r & 1][j][lane * 4];
                __builtin_nontemporal_store(v,
                    (floatx4*)(out + ((size_t)t * 64 + wave * 16 + j * 4 + r) * NK + lane * 4));
            }
        }

        t = tn;
    }
}

extern "C" void kernel_launch(void* const* d_in, const int* in_sizes, int n_in,
                              void* d_out, int out_size, void* d_ws, size_t ws_size,
                              hipStream_t stream) {
    const float* x = (const float*)d_in[0];   // [200000, 128] fp32
    const float* c = (const float*)d_in[1];   // [256, 128] fp32
    float* out = (float*)d_out;               // [200000, 256] fp32
    unsigned short* wb = (unsigned short*)d_ws;            // 64 KiB packed B
    float* wcsq = (float*)((char*)d_ws + 65536);           // 1 KiB csq
    const int N = in_sizes[0] / DIM;          // 200000
    const int NT = N / 64;                    // 3125 row-tiles

    prep_clusters<<<dim3(9), dim3(512), 0, stream>>>(c, wb, wcsq);
    const int grid = NT < 512 ? NT : 512;
    cluster_q_v5<<<dim3(grid), dim3(256), 0, stream>>>(x, wb, wcsq, out, NT);
}